// Round 13
// baseline (238.968 us; speedup 1.0000x reference)
//
#include <hip/hip_runtime.h>
#include <hip/hip_bf16.h>
#include <math.h>

#define B_   2
#define H_   16
#define NSEQ 1024
#define DM   1024
#define DKV  64
#define NSPLIT 16
#define LNEPS 1e-5f

typedef __attribute__((ext_vector_type(8))) short s16x8;
typedef __attribute__((ext_vector_type(4))) float f32x4;
typedef __attribute__((ext_vector_type(4))) unsigned u32x4;

__device__ inline short f2bf(float f) {
    __hip_bfloat16 h = __float2bfloat16(f);
    return *reinterpret_cast<short*>(&h);
}
__device__ inline float bf2f(short s) {
    unsigned u = ((unsigned)(unsigned short)s) << 16;
    return __uint_as_float(u);
}

// ---------------- mask dtype detection ----------------
__global__ void detect_mask(const unsigned* __restrict__ mask_words, int* __restrict__ flag) {
    unsigned f = 0;
    for (int i = 0; i < 256; ++i) f |= (mask_words[i] > 1u) ? 1u : 0u;
    *flag = (int)f;   // 1 => packed uint8 bools, 0 => int32 0/1
}

// ---------------- W[K][N] f32 -> Wt[N][K] bf16 (4 weights in one launch) ----------------
__global__ __launch_bounds__(256) void castT4_bf16(
    const float* __restrict__ w0, const float* __restrict__ w1,
    const float* __restrict__ w2, const float* __restrict__ w3,
    short* __restrict__ t0, short* __restrict__ t1,
    short* __restrict__ t2, short* __restrict__ t3) {
    const float* W = blockIdx.z == 0 ? w0 : (blockIdx.z == 1 ? w1 : (blockIdx.z == 2 ? w2 : w3));
    short* Wt      = blockIdx.z == 0 ? t0 : (blockIdx.z == 1 ? t1 : (blockIdx.z == 2 ? t2 : t3));
    __shared__ float tl[32][33];
    const int k0 = blockIdx.y * 32, n0 = blockIdx.x * 32;
    const int r = threadIdx.x >> 3, c4 = (threadIdx.x & 7) * 4;
    *(float4*)&tl[r][c4] = *(const float4*)(W + (size_t)(k0 + r) * DM + n0 + c4);
    __syncthreads();
    unsigned u0 = (unsigned short)f2bf(tl[c4+0][r]) | ((unsigned)(unsigned short)f2bf(tl[c4+1][r]) << 16);
    unsigned u1 = (unsigned short)f2bf(tl[c4+2][r]) | ((unsigned)(unsigned short)f2bf(tl[c4+3][r]) << 16);
    uint2 pk; pk.x = u0; pk.y = u1;
    *(uint2*)(Wt + (size_t)(n0 + r) * DM + k0 + c4) = pk;
}

// ---------------- shared GEMM core pieces ----------------
__device__ inline void loadAf32(const float* p, s16x8& a0, s16x8& a1) {
    f32x4 v0 = *(const f32x4*)p,       v1 = *(const f32x4*)(p + 4);
    f32x4 v2 = *(const f32x4*)(p + 8), v3 = *(const f32x4*)(p + 12);
    a0[0]=f2bf(v0[0]); a0[1]=f2bf(v0[1]); a0[2]=f2bf(v0[2]); a0[3]=f2bf(v0[3]);
    a0[4]=f2bf(v1[0]); a0[5]=f2bf(v1[1]); a0[6]=f2bf(v1[2]); a0[7]=f2bf(v1[3]);
    a1[0]=f2bf(v2[0]); a1[1]=f2bf(v2[1]); a1[2]=f2bf(v2[2]); a1[3]=f2bf(v2[3]);
    a1[4]=f2bf(v3[0]); a1[5]=f2bf(v3[1]); a1[6]=f2bf(v3[2]); a1[7]=f2bf(v3[3]);
}

// ---------------- fused QKV projection: 3 GEMMs in one launch ----------------
__global__ __launch_bounds__(256) void gemm_qkv(
    const float* __restrict__ qin, const float* __restrict__ kin, const float* __restrict__ vin,
    const short* __restrict__ Wcat,     // Wtq|Wtk|Wtv contiguous, each [DM][DM]
    const float* __restrict__ bq, const float* __restrict__ bk, const float* __restrict__ bv,
    short* __restrict__ Qh, short* __restrict__ Kh, short* __restrict__ Vth)
{
    const int t  = threadIdx.x;
    const int wv = t >> 6, l = t & 63, lg = l >> 4, li = l & 15;
    const int wr = wv >> 1, wc = wv & 1;
    const int c0g = blockIdx.x * 64, m0 = blockIdx.y * 64;
    const int sel = c0g >> 10;              // 0=q 1=k 2=v
    const int c0  = c0g & 1023;
    const float* A    = sel == 0 ? qin : (sel == 1 ? kin : vin);
    const short* Wt   = Wcat + (size_t)sel * DM * DM;
    const float* bias = sel == 0 ? bq : (sel == 1 ? bk : bv);
    short* outp       = sel == 0 ? Qh : (sel == 1 ? Kh : Vth);
    const int mode    = sel == 2 ? 2 : 1;

    __shared__ short Asl[64 * 64];
    __shared__ short Bsl[64 * 64];

    f32x4 acc[2][2] = {};
    const int sr = t >> 2, scol = (t & 3) * 16;
    const int sw = (sr & 7) << 3;

    s16x8 a0, a1;
    loadAf32(A + (size_t)(m0 + sr) * DM + scol, a0, a1);
    s16x8 b0 = *(const s16x8*)(Wt + (size_t)(c0 + sr) * DM + scol);
    s16x8 b1 = *(const s16x8*)(Wt + (size_t)(c0 + sr) * DM + scol + 8);

    for (int k0 = 0; k0 < DM; k0 += 64) {
        __syncthreads();
        *(s16x8*)&Asl[sr * 64 + (scol ^ sw)]       = a0;
        *(s16x8*)&Asl[sr * 64 + ((scol + 8) ^ sw)] = a1;
        *(s16x8*)&Bsl[sr * 64 + (scol ^ sw)]       = b0;
        *(s16x8*)&Bsl[sr * 64 + ((scol + 8) ^ sw)] = b1;
        __syncthreads();
        if (k0 + 64 < DM) {
            loadAf32(A + (size_t)(m0 + sr) * DM + k0 + 64 + scol, a0, a1);
            b0 = *(const s16x8*)(Wt + (size_t)(c0 + sr) * DM + k0 + 64 + scol);
            b1 = *(const s16x8*)(Wt + (size_t)(c0 + sr) * DM + k0 + 64 + scol + 8);
        }
        #pragma unroll
        for (int kh = 0; kh < 2; ++kh) {
            s16x8 af[2], bf[2];
            #pragma unroll
            for (int fi = 0; fi < 2; ++fi) {
                const int row = wr * 32 + fi * 16 + li;
                af[fi] = *(const s16x8*)&Asl[row * 64 + ((kh * 32 + lg * 8) ^ ((row & 7) << 3))];
            }
            #pragma unroll
            for (int fj = 0; fj < 2; ++fj) {
                const int row = wc * 32 + fj * 16 + li;
                bf[fj] = *(const s16x8*)&Bsl[row * 64 + ((kh * 32 + lg * 8) ^ ((row & 7) << 3))];
            }
            #pragma unroll
            for (int fi = 0; fi < 2; ++fi)
                #pragma unroll
                for (int fj = 0; fj < 2; ++fj)
                    acc[fi][fj] = __builtin_amdgcn_mfma_f32_16x16x32_bf16(af[fi], bf[fj], acc[fi][fj], 0, 0, 0);
        }
    }

    const int hh = c0 >> 6;
    #pragma unroll
    for (int fi = 0; fi < 2; ++fi) {
        #pragma unroll
        for (int j = 0; j < 4; ++j) {
            const int m = m0 + wr * 32 + fi * 16 + lg * 4 + j;
            const int bb = m >> 10, n = m & (NSEQ - 1);
            #pragma unroll
            for (int fj = 0; fj < 2; ++fj) {
                const int cc = wc * 32 + fj * 16 + li;
                float v = acc[fi][fj][j] + bias[c0 + cc];
                if (mode == 1)
                    outp[(((size_t)(bb * H_ + hh) * NSEQ) + n) * DKV + cc] = f2bf(v);
                else
                    outp[(((size_t)(bb * H_ + hh) * DKV) + cc) * NSEQ + n] = f2bf(v);
            }
        }
    }
}

// ---------------- out-proj GEMM: Yb = Ob @ Wto^T + bo + resid (f32 out) ----------------
__global__ __launch_bounds__(256) void gemm_out(
    const short* __restrict__ A, const short* __restrict__ Wt,
    const float* __restrict__ bias, const float* __restrict__ resid,
    float* __restrict__ outp)
{
    const int t  = threadIdx.x;
    const int wv = t >> 6, l = t & 63, lg = l >> 4, li = l & 15;
    const int wr = wv >> 1, wc = wv & 1;
    const int c0 = blockIdx.x * 64, m0 = blockIdx.y * 64;

    __shared__ short Asl[64 * 64];
    __shared__ short Bsl[64 * 64];

    f32x4 acc[2][2] = {};
    const int sr = t >> 2, scol = (t & 3) * 16;
    const int sw = (sr & 7) << 3;

    s16x8 a0 = *(const s16x8*)(A + (size_t)(m0 + sr) * DM + scol);
    s16x8 a1 = *(const s16x8*)(A + (size_t)(m0 + sr) * DM + scol + 8);
    s16x8 b0 = *(const s16x8*)(Wt + (size_t)(c0 + sr) * DM + scol);
    s16x8 b1 = *(const s16x8*)(Wt + (size_t)(c0 + sr) * DM + scol + 8);

    for (int k0 = 0; k0 < DM; k0 += 64) {
        __syncthreads();
        *(s16x8*)&Asl[sr * 64 + (scol ^ sw)]       = a0;
        *(s16x8*)&Asl[sr * 64 + ((scol + 8) ^ sw)] = a1;
        *(s16x8*)&Bsl[sr * 64 + (scol ^ sw)]       = b0;
        *(s16x8*)&Bsl[sr * 64 + ((scol + 8) ^ sw)] = b1;
        __syncthreads();
        if (k0 + 64 < DM) {
            a0 = *(const s16x8*)(A + (size_t)(m0 + sr) * DM + k0 + 64 + scol);
            a1 = *(const s16x8*)(A + (size_t)(m0 + sr) * DM + k0 + 64 + scol + 8);
            b0 = *(const s16x8*)(Wt + (size_t)(c0 + sr) * DM + k0 + 64 + scol);
            b1 = *(const s16x8*)(Wt + (size_t)(c0 + sr) * DM + k0 + 64 + scol + 8);
        }
        #pragma unroll
        for (int kh = 0; kh < 2; ++kh) {
            s16x8 af[2], bf[2];
            #pragma unroll
            for (int fi = 0; fi < 2; ++fi) {
                const int row = wr * 32 + fi * 16 + li;
                af[fi] = *(const s16x8*)&Asl[row * 64 + ((kh * 32 + lg * 8) ^ ((row & 7) << 3))];
            }
            #pragma unroll
            for (int fj = 0; fj < 2; ++fj) {
                const int row = wc * 32 + fj * 16 + li;
                bf[fj] = *(const s16x8*)&Bsl[row * 64 + ((kh * 32 + lg * 8) ^ ((row & 7) << 3))];
            }
            #pragma unroll
            for (int fi = 0; fi < 2; ++fi)
                #pragma unroll
                for (int fj = 0; fj < 2; ++fj)
                    acc[fi][fj] = __builtin_amdgcn_mfma_f32_16x16x32_bf16(af[fi], bf[fj], acc[fi][fj], 0, 0, 0);
        }
    }

    #pragma unroll
    for (int fi = 0; fi < 2; ++fi) {
        #pragma unroll
        for (int j = 0; j < 4; ++j) {
            const int m = m0 + wr * 32 + fi * 16 + lg * 4 + j;
            #pragma unroll
            for (int fj = 0; fj < 2; ++fj) {
                const int c = c0 + wc * 32 + fj * 16 + li;
                outp[(size_t)m * DM + c] = acc[fi][fj][j] + bias[c] + resid[(size_t)m * DM + c];
            }
        }
    }
}

// ---------------- wgt+mask prefetch, pre-fused: wq = masked ? -1 : 0.125*w ----------------
__device__ __forceinline__ void wload(
    const float* __restrict__ wrow, const unsigned char* __restrict__ Mb,
    const unsigned* __restrict__ Mi, size_t moff, int mmode, int kc, int lg, f32x4* wq)
{
    #pragma unroll
    for (int nt = 0; nt < 4; ++nt) {
        const int k4 = kc + nt*16 + lg*4;
        f32x4 w4 = *(const f32x4*)(wrow + k4);
        unsigned mm[4];
        if (mmode) {
            unsigned u = *(const unsigned*)(Mb + moff + k4);
            mm[0]=u&0xffu; mm[1]=(u>>8)&0xffu; mm[2]=(u>>16)&0xffu; mm[3]=u>>24;
        } else {
            u32x4 mi = *(const u32x4*)(Mi + moff + k4);
            mm[0]=mi[0]; mm[1]=mi[1]; mm[2]=mi[2]; mm[3]=mi[3];
        }
        f32x4 o;
        #pragma unroll
        for (int r = 0; r < 4; ++r) o[r] = mm[r] ? -1.0f : 0.125f * w4[r];
        wq[nt] = o;
    }
}

// ---------------- flash attention, NSPLIT=16 ----------------
// Round-10 lesson: with default launch_bounds the compiler targets max occupancy
// -> 64-VGPR budget -> the 26 loads CANNOT coexist -> load/wait/consume groups
// -> ~1 load in flight -> 1.4 TB/s latency cap, invariant across rounds 3-10.
// Fix: __launch_bounds__(256, 2) = min 2 waves/SIMD = up to ~256 VGPR budget,
// so all loads issue before the asm join and fly concurrently (~416B/lane MLP).
__global__ __launch_bounds__(256, 2) void attn_one(
    const short* __restrict__ Qb, const short* __restrict__ Kb, const short* __restrict__ Vt,
    const void* __restrict__ mask, const float* __restrict__ wgt,
    const int* __restrict__ flagp, short* __restrict__ Opart,
    float* __restrict__ mpart, float* __restrict__ lpart)
{
    const int t  = threadIdx.x;
    const int wv = t >> 6;
    const int l  = t & 63;
    const int lg = l >> 4;
    const int li = l & 15;
    const int qt = blockIdx.x >> 4;          // 0..15
    const int sp = blockIdx.x & (NSPLIT-1);  // 0..15
    const int h  = blockIdx.y, b = blockIdx.z;
    const size_t bh = (size_t)b * H_ + h;
    const int qrow = qt*64 + wv*16 + li;     // softmax-layout row
    const int kc = sp * 64;

    __shared__ short Plds[4][16][80];

    const short* Qp = Qb + (bh * NSEQ + qt*64 + wv*16) * DKV;
    const short* Kp = Kb + bh * NSEQ * DKV;
    const short* Vp = Vt + bh * DKV * NSEQ;
    const float* wrow = wgt + (bh * NSEQ + qrow) * NSEQ;
    const size_t moff = (bh * NSEQ + qrow) * NSEQ;
    const int mmode = *flagp;
    const unsigned* Mi = (const unsigned*)mask;
    const unsigned char* Mb = (const unsigned char*)mask;

    // ---- issue ALL loads ----
    f32x4 wq[4];
    wload(wrow, Mb, Mi, moff, mmode, kc, lg, wq);

    s16x8 qa[2];
    qa[0] = *(const s16x8*)(Qp + (size_t)li * DKV + lg*8);
    qa[1] = *(const s16x8*)(Qp + (size_t)li * DKV + 32 + lg*8);

    s16x8 kf[8];
    #pragma unroll
    for (int dc = 0; dc < 2; ++dc)
        #pragma unroll
        for (int nt = 0; nt < 4; ++nt)
            kf[dc*4+nt] = *(const s16x8*)(Kp + (size_t)(kc + nt*16 + li) * DKV + dc*32 + lg*8);

    s16x8 vf[8];
    #pragma unroll
    for (int kch = 0; kch < 2; ++kch)
        #pragma unroll
        for (int dt = 0; dt < 4; ++dt)
            vf[kch*4+dt] = *(const s16x8*)(Vp + (size_t)(dt*16 + li) * NSEQ + kc + kch*32 + lg*8);

    // ---- force materialization: single join, all loads concurrently in flight ----
    asm volatile("" ::
        "v"(qa[0]), "v"(qa[1]),
        "v"(kf[0]), "v"(kf[1]), "v"(kf[2]), "v"(kf[3]),
        "v"(kf[4]), "v"(kf[5]), "v"(kf[6]), "v"(kf[7]),
        "v"(vf[0]), "v"(vf[1]), "v"(vf[2]), "v"(vf[3]),
        "v"(vf[4]), "v"(vf[5]), "v"(vf[6]), "v"(vf[7]),
        "v"(wq[0]), "v"(wq[1]), "v"(wq[2]), "v"(wq[3]));

    // ---- S^T = K * Q^T : sc[nt][r] = S[q=li][key = kc + nt*16 + lg*4 + r] ----
    f32x4 sc[4] = {};
    #pragma unroll
    for (int dc = 0; dc < 2; ++dc)
        #pragma unroll
        for (int nt = 0; nt < 4; ++nt)
            sc[nt] = __builtin_amdgcn_mfma_f32_16x16x32_bf16(kf[dc*4+nt], qa[dc], sc[nt], 0, 0, 0);

    // ---- single-pass softmax (softmax layout) ----
    float sv[16];
    float cmax = -1e30f;
    #pragma unroll
    for (int nt = 0; nt < 4; ++nt)
        #pragma unroll
        for (int r = 0; r < 4; ++r) {
            float wf = wq[nt][r];                  // -1 sentinel or 0.125*w
            float s = sc[nt][r] * wf;
            s = (wf < 0.f) ? -1e30f : s;
            sv[nt*4 + r] = s;
            cmax = fmaxf(cmax, s);
        }
    cmax = fmaxf(cmax, __shfl_xor(cmax, 16));
    cmax = fmaxf(cmax, __shfl_xor(cmax, 32));

    float csum = 0.f;
    #pragma unroll
    for (int nt = 0; nt < 4; ++nt) {
        float p0 = __expf(sv[nt*4+0] - cmax), p1 = __expf(sv[nt*4+1] - cmax);
        float p2 = __expf(sv[nt*4+2] - cmax), p3 = __expf(sv[nt*4+3] - cmax);
        csum += p0 + p1 + p2 + p3;
        unsigned u0 = (unsigned short)f2bf(p0) | ((unsigned)(unsigned short)f2bf(p1) << 16);
        unsigned u1 = (unsigned short)f2bf(p2) | ((unsigned)(unsigned short)f2bf(p3) << 16);
        uint2 pk; pk.x = u0; pk.y = u1;
        *(uint2*)&Plds[wv][li][nt*16 + lg*4] = pk;
    }
    csum += __shfl_xor(csum, 16);
    csum += __shfl_xor(csum, 32);

    // ---- PV ----
    f32x4 oacc[4] = {};
    #pragma unroll
    for (int kch = 0; kch < 2; ++kch) {
        s16x8 pa = *(const s16x8*)&Plds[wv][li][kch*32 + lg*8];
        #pragma unroll
        for (int dt = 0; dt < 4; ++dt)
            oacc[dt] = __builtin_amdgcn_mfma_f32_16x16x32_bf16(pa, vf[kch*4+dt], oacc[dt], 0, 0, 0);
    }

    // ---- write partials ----
    const size_t SBH = (size_t)B_ * H_ * NSEQ;
    if (lg == 0) {
        mpart[(size_t)sp * SBH + bh * NSEQ + qrow] = cmax;
        lpart[(size_t)sp * SBH + bh * NSEQ + qrow] = csum;
    }
    #pragma unroll
    for (int dt = 0; dt < 4; ++dt)
        #pragma unroll
        for (int r = 0; r < 4; ++r)
            Opart[((size_t)sp * SBH + bh * NSEQ + qt*64 + wv*16 + lg*4 + r) * DKV + dt*16 + li]
                = f2bf(oacc[dt][r]);
}

// ---------------- split combine: merge 16 partials, normalize ----------------
// launch_bounds(256,1): allow big VGPR budget so the 16 m + 16 l + 16 O loads
// all fly concurrently instead of serializing at a 64-reg budget.
__global__ __launch_bounds__(256, 1) void attn_combine(
    const short* __restrict__ Opart, const float* __restrict__ mpart,
    const float* __restrict__ lpart, short* __restrict__ Ob)
{
    const size_t SBH = (size_t)B_ * H_ * NSEQ;
    const int R = blockIdx.x * 4 + (threadIdx.x >> 6);
    const int d = threadIdx.x & 63;
    const int bh = R >> 10, n = R & (NSEQ - 1);
    const int b = bh >> 4, h = bh & (H_ - 1);

    float ms[NSPLIT], ls[NSPLIT], ov[NSPLIT];
    #pragma unroll
    for (int s = 0; s < NSPLIT; ++s) {
        ms[s] = mpart[(size_t)s * SBH + R];
        ls[s] = lpart[(size_t)s * SBH + R];
        ov[s] = bf2f(Opart[((size_t)s * SBH + R) * DKV + d]);
    }
    asm volatile("" ::
        "v"(ms[0]), "v"(ms[3]), "v"(ms[7]), "v"(ms[11]), "v"(ms[15]),
        "v"(ls[0]), "v"(ls[3]), "v"(ls[7]), "v"(ls[11]), "v"(ls[15]),
        "v"(ov[0]), "v"(ov[3]), "v"(ov[7]), "v"(ov[11]), "v"(ov[15]));
    float mstar = -1e30f;
    #pragma unroll
    for (int s = 0; s < NSPLIT; ++s) mstar = fmaxf(mstar, ms[s]);
    float lstar = 0.f, acc = 0.f;
    #pragma unroll
    for (int s = 0; s < NSPLIT; ++s) {
        float w = __expf(ms[s] - mstar);
        lstar += w * ls[s];
        acc   += w * ov[s];
    }
    Ob[((size_t)b * NSEQ + n) * DM + h * DKV + d] = f2bf(acc / lstar);
}

// ---------------- residual + LayerNorm ----------------
__global__ __launch_bounds__(256) void ln_kernel(
    const float* __restrict__ Y, const float* __restrict__ gamma,
    const float* __restrict__ beta, float* __restrict__ out)
{
    const int row = blockIdx.x;
    const int t = threadIdx.x;
    const float* y = Y + (size_t)row * DM;
    float4 x = *(const float4*)(y + t*4);
    __shared__ float red[4];
    float s = x.x + x.y + x.z + x.w;
    #pragma unroll
    for (int off = 32; off > 0; off >>= 1) s += __shfl_xor(s, off);
    if ((t & 63) == 0) red[t >> 6] = s;
    __syncthreads();
    float mean = (red[0]+red[1]+red[2]+red[3]) * (1.0f/DM);
    float d0 = x.x-mean, d1 = x.y-mean, d2 = x.z-mean, d3 = x.w-mean;
    float sq = d0*d0 + d1*d1 + d2*d2 + d3*d3;
    __syncthreads();
    #pragma unroll
    for (int off = 32; off > 0; off >>= 1) sq += __shfl_xor(sq, off);
    if ((t & 63) == 0) red[t >> 6] = sq;
    __syncthreads();
    float var = (red[0]+red[1]+red[2]+red[3]) * (1.0f/DM);
    float rstd = rsqrtf(var + LNEPS);
    int c = t * 4;
    float4 g  = *(const float4*)(gamma + c);
    float4 bb = *(const float4*)(beta + c);
    float4 o;
    o.x = d0*rstd*g.x + bb.x;
    o.y = d1*rstd*g.y + bb.y;
    o.z = d2*rstd*g.z + bb.z;
    o.w = d3*rstd*g.w + bb.w;
    *(float4*)(out + (size_t)row*DM + c) = o;
}

extern "C" void kernel_launch(void* const* d_in, const int* in_sizes, int n_in,
                              void* d_out, int out_size, void* d_ws, size_t ws_size,
                              hipStream_t stream)
{
    const float* queries = (const float*)d_in[0];
    const float* keys    = (const float*)d_in[1];
    const float* values  = (const float*)d_in[2];
    const void*  mask    = d_in[3];
    const float* wgt     = (const float*)d_in[4];
    const float* Wq = (const float*)d_in[5];  const float* bq = (const float*)d_in[6];
    const float* Wk = (const float*)d_in[7];  const float* bk = (const float*)d_in[8];
    const float* Wv = (const float*)d_in[9];  const float* bv = (const float*)d_in[10];
    const float* Wo = (const float*)d_in[11]; const float* bo = (const float*)d_in[12];
    const float* gamma = (const float*)d_in[13]; const float* beta = (const float*)d_in[14];
    float* out = (float*)d_out;

    const size_t SZ  = (size_t)B_ * NSEQ * DM;     // 2M elements
    const size_t WSZ = (size_t)DM * DM;            // 1M elements
    const size_t SBH = (size_t)B_ * H_ * NSEQ;     // 32K rows

    char* ws = (char*)d_ws;
    int*   flag = (int*)ws;
    short* Wtq = (short*)(ws + 256);               // Wtq|Wtk|Wtv contiguous = Wcat
    short* Wtk = Wtq + WSZ;
    short* Wtv = Wtk + WSZ;
    short* Wto = Wtv + WSZ;
    short* Qh  = Wto + WSZ;
    short* Kh  = Qh + SZ;
    short* Vth = Kh + SZ;
    short* Opart = Vth + SZ;                       // 16 x 4 MB bf16
    float* mpart = (float*)(Opart + (size_t)NSPLIT * SBH * DKV);
    float* lpart = mpart + NSPLIT * SBH;
    short* Ob  = (short*)(lpart + NSPLIT * SBH);
    float* Yb  = (float*)Opart;                    // alias: Opart dead after combine

    detect_mask<<<1, 1, 0, stream>>>((const unsigned*)mask, flag);
    castT4_bf16<<<dim3(32, 32, 4), 256, 0, stream>>>(Wq, Wk, Wv, Wo, Wtq, Wtk, Wtv, Wto);

    gemm_qkv<<<dim3(48, 32), 256, 0, stream>>>(queries, keys, values, Wtq,
                                               bq, bk, bv, Qh, Kh, Vth);

    attn_one<<<dim3(16 * NSPLIT, H_, B_), 256, 0, stream>>>(
        Qh, Kh, Vth, mask, wgt, flag, Opart, mpart, lpart);
    attn_combine<<<dim3((int)(SBH / 4)), 256, 0, stream>>>(Opart, mpart, lpart, Ob);

    gemm_out<<<dim3(16, 32), 256, 0, stream>>>(Ob, Wto, bo, queries, Yb);
    ln_kernel<<<dim3(B_*NSEQ), 256, 0, stream>>>(Yb, gamma, beta, out);
}

// Round 14
// 219.598 us; speedup vs baseline: 1.0882x; 1.0882x over previous
//
#include <hip/hip_runtime.h>
#include <hip/hip_bf16.h>
#include <math.h>

#define B_   2
#define H_   16
#define NSEQ 1024
#define DM   1024
#define DKV  64
#define NSPLIT 16
#define LNEPS 1e-5f

typedef __attribute__((ext_vector_type(8))) short s16x8;
typedef __attribute__((ext_vector_type(4))) float f32x4;
typedef __attribute__((ext_vector_type(4))) unsigned u32x4;

__device__ inline short f2bf(float f) {
    __hip_bfloat16 h = __float2bfloat16(f);
    return *reinterpret_cast<short*>(&h);
}
__device__ inline float bf2f(short s) {
    unsigned u = ((unsigned)(unsigned short)s) << 16;
    return __uint_as_float(u);
}

// async global->LDS; LDS dest = wave-uniform base + lane*width; global src per-lane.
__device__ __forceinline__ void gll16(const void* g, void* l) {
    __builtin_amdgcn_global_load_lds(
        (const __attribute__((address_space(1))) unsigned int*)g,
        (__attribute__((address_space(3))) unsigned int*)l, 16, 0, 0);
}
__device__ __forceinline__ void gll4(const void* g, void* l) {
    __builtin_amdgcn_global_load_lds(
        (const __attribute__((address_space(1))) unsigned int*)g,
        (__attribute__((address_space(3))) unsigned int*)l, 4, 0, 0);
}

#define SYNC_STAGE do { asm volatile("s_waitcnt vmcnt(0)" ::: "memory"); __syncthreads(); } while (0)

// ---------------- mask dtype detection ----------------
__global__ void detect_mask(const unsigned* __restrict__ mask_words, int* __restrict__ flag) {
    unsigned f = 0;
    for (int i = 0; i < 256; ++i) f |= (mask_words[i] > 1u) ? 1u : 0u;
    *flag = (int)f;   // 1 => packed uint8 bools, 0 => int32 0/1
}

// ---------------- W[K][N] f32 -> Wt[N][K] bf16 (4 weights in one launch) ----------------
__global__ __launch_bounds__(256) void castT4_bf16(
    const float* __restrict__ w0, const float* __restrict__ w1,
    const float* __restrict__ w2, const float* __restrict__ w3,
    short* __restrict__ t0, short* __restrict__ t1,
    short* __restrict__ t2, short* __restrict__ t3) {
    const float* W = blockIdx.z == 0 ? w0 : (blockIdx.z == 1 ? w1 : (blockIdx.z == 2 ? w2 : w3));
    short* Wt      = blockIdx.z == 0 ? t0 : (blockIdx.z == 1 ? t1 : (blockIdx.z == 2 ? t2 : t3));
    __shared__ float tl[32][33];
    const int k0 = blockIdx.y * 32, n0 = blockIdx.x * 32;
    const int r = threadIdx.x >> 3, c4 = (threadIdx.x & 7) * 4;
    *(float4*)&tl[r][c4] = *(const float4*)(W + (size_t)(k0 + r) * DM + n0 + c4);
    __syncthreads();
    unsigned u0 = (unsigned short)f2bf(tl[c4+0][r]) | ((unsigned)(unsigned short)f2bf(tl[c4+1][r]) << 16);
    unsigned u1 = (unsigned short)f2bf(tl[c4+2][r]) | ((unsigned)(unsigned short)f2bf(tl[c4+3][r]) << 16);
    uint2 pk; pk.x = u0; pk.y = u1;
    *(uint2*)(Wt + (size_t)(n0 + r) * DM + k0 + c4) = pk;
}

// ---------------- shared GEMM core pieces ----------------
__device__ inline void loadAf32(const float* p, s16x8& a0, s16x8& a1) {
    f32x4 v0 = *(const f32x4*)p,       v1 = *(const f32x4*)(p + 4);
    f32x4 v2 = *(const f32x4*)(p + 8), v3 = *(const f32x4*)(p + 12);
    a0[0]=f2bf(v0[0]); a0[1]=f2bf(v0[1]); a0[2]=f2bf(v0[2]); a0[3]=f2bf(v0[3]);
    a0[4]=f2bf(v1[0]); a0[5]=f2bf(v1[1]); a0[6]=f2bf(v1[2]); a0[7]=f2bf(v1[3]);
    a1[0]=f2bf(v2[0]); a1[1]=f2bf(v2[1]); a1[2]=f2bf(v2[2]); a1[3]=f2bf(v2[3]);
    a1[4]=f2bf(v3[0]); a1[5]=f2bf(v3[1]); a1[6]=f2bf(v3[2]); a1[7]=f2bf(v3[3]);
}

// ---------------- fused QKV projection: 3 GEMMs in one launch ----------------
__global__ __launch_bounds__(256) void gemm_qkv(
    const float* __restrict__ qin, const float* __restrict__ kin, const float* __restrict__ vin,
    const short* __restrict__ Wcat,     // Wtq|Wtk|Wtv contiguous, each [DM][DM]
    const float* __restrict__ bq, const float* __restrict__ bk, const float* __restrict__ bv,
    short* __restrict__ Qh, short* __restrict__ Kh, short* __restrict__ Vth)
{
    const int t  = threadIdx.x;
    const int wv = t >> 6, l = t & 63, lg = l >> 4, li = l & 15;
    const int wr = wv >> 1, wc = wv & 1;
    const int c0g = blockIdx.x * 64, m0 = blockIdx.y * 64;
    const int sel = c0g >> 10;              // 0=q 1=k 2=v
    const int c0  = c0g & 1023;
    const float* A    = sel == 0 ? qin : (sel == 1 ? kin : vin);
    const short* Wt   = Wcat + (size_t)sel * DM * DM;
    const float* bias = sel == 0 ? bq : (sel == 1 ? bk : bv);
    short* outp       = sel == 0 ? Qh : (sel == 1 ? Kh : Vth);
    const int mode    = sel == 2 ? 2 : 1;

    __shared__ short Asl[64 * 64];
    __shared__ short Bsl[64 * 64];

    f32x4 acc[2][2] = {};
    const int sr = t >> 2, scol = (t & 3) * 16;
    const int sw = (sr & 7) << 3;

    s16x8 a0, a1;
    loadAf32(A + (size_t)(m0 + sr) * DM + scol, a0, a1);
    s16x8 b0 = *(const s16x8*)(Wt + (size_t)(c0 + sr) * DM + scol);
    s16x8 b1 = *(const s16x8*)(Wt + (size_t)(c0 + sr) * DM + scol + 8);

    for (int k0 = 0; k0 < DM; k0 += 64) {
        __syncthreads();
        *(s16x8*)&Asl[sr * 64 + (scol ^ sw)]       = a0;
        *(s16x8*)&Asl[sr * 64 + ((scol + 8) ^ sw)] = a1;
        *(s16x8*)&Bsl[sr * 64 + (scol ^ sw)]       = b0;
        *(s16x8*)&Bsl[sr * 64 + ((scol + 8) ^ sw)] = b1;
        __syncthreads();
        if (k0 + 64 < DM) {
            loadAf32(A + (size_t)(m0 + sr) * DM + k0 + 64 + scol, a0, a1);
            b0 = *(const s16x8*)(Wt + (size_t)(c0 + sr) * DM + k0 + 64 + scol);
            b1 = *(const s16x8*)(Wt + (size_t)(c0 + sr) * DM + k0 + 64 + scol + 8);
        }
        #pragma unroll
        for (int kh = 0; kh < 2; ++kh) {
            s16x8 af[2], bf[2];
            #pragma unroll
            for (int fi = 0; fi < 2; ++fi) {
                const int row = wr * 32 + fi * 16 + li;
                af[fi] = *(const s16x8*)&Asl[row * 64 + ((kh * 32 + lg * 8) ^ ((row & 7) << 3))];
            }
            #pragma unroll
            for (int fj = 0; fj < 2; ++fj) {
                const int row = wc * 32 + fj * 16 + li;
                bf[fj] = *(const s16x8*)&Bsl[row * 64 + ((kh * 32 + lg * 8) ^ ((row & 7) << 3))];
            }
            #pragma unroll
            for (int fi = 0; fi < 2; ++fi)
                #pragma unroll
                for (int fj = 0; fj < 2; ++fj)
                    acc[fi][fj] = __builtin_amdgcn_mfma_f32_16x16x32_bf16(af[fi], bf[fj], acc[fi][fj], 0, 0, 0);
        }
    }

    const int hh = c0 >> 6;
    #pragma unroll
    for (int fi = 0; fi < 2; ++fi) {
        #pragma unroll
        for (int j = 0; j < 4; ++j) {
            const int m = m0 + wr * 32 + fi * 16 + lg * 4 + j;
            const int bb = m >> 10, n = m & (NSEQ - 1);
            #pragma unroll
            for (int fj = 0; fj < 2; ++fj) {
                const int cc = wc * 32 + fj * 16 + li;
                float v = acc[fi][fj][j] + bias[c0 + cc];
                if (mode == 1)
                    outp[(((size_t)(bb * H_ + hh) * NSEQ) + n) * DKV + cc] = f2bf(v);
                else
                    outp[(((size_t)(bb * H_ + hh) * DKV) + cc) * NSEQ + n] = f2bf(v);
            }
        }
    }
}

// ---------------- out-proj GEMM: Yb = Ob @ Wto^T + bo + resid (f32 out) ----------------
__global__ __launch_bounds__(256) void gemm_out(
    const short* __restrict__ A, const short* __restrict__ Wt,
    const float* __restrict__ bias, const float* __restrict__ resid,
    float* __restrict__ outp)
{
    const int t  = threadIdx.x;
    const int wv = t >> 6, l = t & 63, lg = l >> 4, li = l & 15;
    const int wr = wv >> 1, wc = wv & 1;
    const int c0 = blockIdx.x * 64, m0 = blockIdx.y * 64;

    __shared__ short Asl[64 * 64];
    __shared__ short Bsl[64 * 64];

    f32x4 acc[2][2] = {};
    const int sr = t >> 2, scol = (t & 3) * 16;
    const int sw = (sr & 7) << 3;

    s16x8 a0 = *(const s16x8*)(A + (size_t)(m0 + sr) * DM + scol);
    s16x8 a1 = *(const s16x8*)(A + (size_t)(m0 + sr) * DM + scol + 8);
    s16x8 b0 = *(const s16x8*)(Wt + (size_t)(c0 + sr) * DM + scol);
    s16x8 b1 = *(const s16x8*)(Wt + (size_t)(c0 + sr) * DM + scol + 8);

    for (int k0 = 0; k0 < DM; k0 += 64) {
        __syncthreads();
        *(s16x8*)&Asl[sr * 64 + (scol ^ sw)]       = a0;
        *(s16x8*)&Asl[sr * 64 + ((scol + 8) ^ sw)] = a1;
        *(s16x8*)&Bsl[sr * 64 + (scol ^ sw)]       = b0;
        *(s16x8*)&Bsl[sr * 64 + ((scol + 8) ^ sw)] = b1;
        __syncthreads();
        if (k0 + 64 < DM) {
            a0 = *(const s16x8*)(A + (size_t)(m0 + sr) * DM + k0 + 64 + scol);
            a1 = *(const s16x8*)(A + (size_t)(m0 + sr) * DM + k0 + 64 + scol + 8);
            b0 = *(const s16x8*)(Wt + (size_t)(c0 + sr) * DM + k0 + 64 + scol);
            b1 = *(const s16x8*)(Wt + (size_t)(c0 + sr) * DM + k0 + 64 + scol + 8);
        }
        #pragma unroll
        for (int kh = 0; kh < 2; ++kh) {
            s16x8 af[2], bf[2];
            #pragma unroll
            for (int fi = 0; fi < 2; ++fi) {
                const int row = wr * 32 + fi * 16 + li;
                af[fi] = *(const s16x8*)&Asl[row * 64 + ((kh * 32 + lg * 8) ^ ((row & 7) << 3))];
            }
            #pragma unroll
            for (int fj = 0; fj < 2; ++fj) {
                const int row = wc * 32 + fj * 16 + li;
                bf[fj] = *(const s16x8*)&Bsl[row * 64 + ((kh * 32 + lg * 8) ^ ((row & 7) << 3))];
            }
            #pragma unroll
            for (int fi = 0; fi < 2; ++fi)
                #pragma unroll
                for (int fj = 0; fj < 2; ++fj)
                    acc[fi][fj] = __builtin_amdgcn_mfma_f32_16x16x32_bf16(af[fi], bf[fj], acc[fi][fj], 0, 0, 0);
        }
    }

    #pragma unroll
    for (int fi = 0; fi < 2; ++fi) {
        #pragma unroll
        for (int j = 0; j < 4; ++j) {
            const int m = m0 + wr * 32 + fi * 16 + lg * 4 + j;
            #pragma unroll
            for (int fj = 0; fj < 2; ++fj) {
                const int c = c0 + wc * 32 + fj * 16 + li;
                outp[(size_t)m * DM + c] = acc[fi][fj][j] + bias[c] + resid[(size_t)m * DM + c];
            }
        }
    }
}

// ---------------- flash attention, NSPLIT=16, FULL async-LDS staging ----------------
// Rounds 3-13 lesson: VGPR-path loads serialize (compiler sinks loads; ~1 in flight
// -> 1.5 TB/s latency cap; launch_bounds/asm-join don't change it). global_load_lds
// needs NO VGPRs and allows up to 63 outstanding. So stage K, V, AND the dominant
// wgt+mask streams as one 48-instruction async burst (36 KB/block), one vmcnt(0)+
// barrier, then compute from LDS. Fragment-linear LDS layouts (slot = exactly what
// lane l reads) -> conflict-free lane-linear ds_reads; all 4 waves reading the same
// K/V fragment broadcast (free).
__global__ __launch_bounds__(256) void attn_one(
    const short* __restrict__ Qb, const short* __restrict__ Kb, const short* __restrict__ Vt,
    const void* __restrict__ mask, const float* __restrict__ wgt,
    const int* __restrict__ flagp, short* __restrict__ Opart,
    float* __restrict__ mpart, float* __restrict__ lpart)
{
    const int t  = threadIdx.x;
    const int wv = t >> 6;
    const int l  = t & 63;
    const int lg = l >> 4;
    const int li = l & 15;
    const int qt = blockIdx.x >> 4;          // 0..15
    const int sp = blockIdx.x & (NSPLIT-1);  // 0..15
    const int h  = blockIdx.y, b = blockIdx.z;
    const size_t bh = (size_t)b * H_ + h;
    const int qrow = qt*64 + wv*16 + li;     // softmax-layout row
    const int kc = sp * 64;

    // fragment-linear LDS: frag f at [f*frag_elems], lane l at +l*(16B or 4B)
    __shared__ short Kl[8 * 512];            // 8 KB : frag (dc*4+nt), lane 16B
    __shared__ short Vl[8 * 512];            // 8 KB : frag (kch*4+dt), lane 16B
    __shared__ float Wl[16 * 256];           // 16 KB: frag (nt*4+wv),  lane 16B (f32x4)
    __shared__ unsigned char Ml[16 * 256];   // 4 KB : frag (nt*4+wv),  lane 4B
    __shared__ short Plds[4][16][80];        // 10 KB

    const short* Qp = Qb + (bh * NSEQ + qt*64 + wv*16) * DKV;
    const short* Kp = Kb + bh * NSEQ * DKV;
    const short* Vp = Vt + bh * DKV * NSEQ;
    const size_t moff = (bh * NSEQ + qrow) * NSEQ;
    const size_t rowT = bh * NSEQ + (size_t)qt * 64;       // tile row base in wgt/mask
    const int mmode = *flagp;
    const unsigned* Mi = (const unsigned*)mask;
    const unsigned char* Mb = (const unsigned char*)mask;

    // ---- async staging burst: 48 x global_load_lds, zero VGPR cost ----
    // wgt/mask frag j = nt*4+wvv: lane l fetches row (wvv*16 + li), cols kc+nt*16+lg*4..+3
    if (wv == 0) {
        #pragma unroll
        for (int i = 0; i < 8; ++i) {        // K frag i = dc*4+nt
            const int nt = i & 3, dc = i >> 2;
            gll16(Kp + (size_t)(kc + nt*16 + li) * DKV + dc*32 + lg*8, Kl + i*512);
        }
        #pragma unroll
        for (int j = 0; j < 4; ++j)
            gll4(Mb + (rowT + (j&3)*16 + li) * NSEQ + kc + (j>>2)*16 + lg*4, Ml + j*256);
    } else if (wv == 1) {
        #pragma unroll
        for (int i = 0; i < 8; ++i) {        // V frag i = kch*4+dt
            const int dt = i & 3, kch = i >> 2;
            gll16(Vp + (size_t)(dt*16 + li) * NSEQ + kc + kch*32 + lg*8, Vl + i*512);
        }
        #pragma unroll
        for (int j = 4; j < 8; ++j)
            gll4(Mb + (rowT + (j&3)*16 + li) * NSEQ + kc + (j>>2)*16 + lg*4, Ml + j*256);
    } else if (wv == 2) {
        #pragma unroll
        for (int j = 0; j < 8; ++j)
            gll16(wgt + (rowT + (j&3)*16 + li) * NSEQ + kc + (j>>2)*16 + lg*4, Wl + j*256);
        #pragma unroll
        for (int j = 8; j < 12; ++j)
            gll4(Mb + (rowT + (j&3)*16 + li) * NSEQ + kc + (j>>2)*16 + lg*4, Ml + j*256);
    } else {
        #pragma unroll
        for (int j = 8; j < 16; ++j)
            gll16(wgt + (rowT + (j&3)*16 + li) * NSEQ + kc + (j>>2)*16 + lg*4, Wl + j*256);
        #pragma unroll
        for (int j = 12; j < 16; ++j)
            gll4(Mb + (rowT + (j&3)*16 + li) * NSEQ + kc + (j>>2)*16 + lg*4, Ml + j*256);
    }

    // Q fragments (tiny; L2/L3-resident)
    s16x8 qa[2];
    qa[0] = *(const s16x8*)(Qp + (size_t)li * DKV + lg*8);
    qa[1] = *(const s16x8*)(Qp + (size_t)li * DKV + 32 + lg*8);

    SYNC_STAGE;

    // ---- S^T = K * Q^T : sc[nt][r] = S[q=li][key = kc + nt*16 + lg*4 + r] ----
    f32x4 sc[4] = {};
    #pragma unroll
    for (int dc = 0; dc < 2; ++dc)
        #pragma unroll
        for (int nt = 0; nt < 4; ++nt) {
            s16x8 kb = *(const s16x8*)&Kl[(dc*4 + nt)*512 + l*8];
            sc[nt] = __builtin_amdgcn_mfma_f32_16x16x32_bf16(kb, qa[dc], sc[nt], 0, 0, 0);
        }

    // ---- single-pass softmax (softmax layout); wgt/mask from LDS frags ----
    float sv[16];
    float cmax = -1e30f;
    #pragma unroll
    for (int nt = 0; nt < 4; ++nt) {
        f32x4 w4 = *(const f32x4*)&Wl[(nt*4 + wv)*256 + l*4];
        unsigned mm[4];
        if (mmode) {
            unsigned u = *(const unsigned*)&Ml[(nt*4 + wv)*256 + l*4];
            mm[0] = u & 0xffu; mm[1] = (u >> 8) & 0xffu;
            mm[2] = (u >> 16) & 0xffu; mm[3] = u >> 24;
        } else {
            u32x4 mi = *(const u32x4*)(Mi + moff + kc + nt*16 + lg*4);
            mm[0] = mi[0]; mm[1] = mi[1]; mm[2] = mi[2]; mm[3] = mi[3];
        }
        #pragma unroll
        for (int r = 0; r < 4; ++r) {
            float s = sc[nt][r] * 0.125f * w4[r];
            s = mm[r] ? -1e30f : s;
            sv[nt*4 + r] = s;
            cmax = fmaxf(cmax, s);
        }
    }
    cmax = fmaxf(cmax, __shfl_xor(cmax, 16));
    cmax = fmaxf(cmax, __shfl_xor(cmax, 32));

    float csum = 0.f;
    #pragma unroll
    for (int nt = 0; nt < 4; ++nt) {
        float p0 = __expf(sv[nt*4+0] - cmax), p1 = __expf(sv[nt*4+1] - cmax);
        float p2 = __expf(sv[nt*4+2] - cmax), p3 = __expf(sv[nt*4+3] - cmax);
        csum += p0 + p1 + p2 + p3;
        unsigned u0 = (unsigned short)f2bf(p0) | ((unsigned)(unsigned short)f2bf(p1) << 16);
        unsigned u1 = (unsigned short)f2bf(p2) | ((unsigned)(unsigned short)f2bf(p3) << 16);
        uint2 pk; pk.x = u0; pk.y = u1;
        *(uint2*)&Plds[wv][li][nt*16 + lg*4] = pk;
    }
    csum += __shfl_xor(csum, 16);
    csum += __shfl_xor(csum, 32);

    // ---- PV from LDS V fragments ----
    f32x4 oacc[4] = {};
    #pragma unroll
    for (int kch = 0; kch < 2; ++kch) {
        s16x8 pa = *(const s16x8*)&Plds[wv][li][kch*32 + lg*8];
        #pragma unroll
        for (int dt = 0; dt < 4; ++dt) {
            s16x8 vb = *(const s16x8*)&Vl[(kch*4 + dt)*512 + l*8];
            oacc[dt] = __builtin_amdgcn_mfma_f32_16x16x32_bf16(pa, vb, oacc[dt], 0, 0, 0);
        }
    }

    // ---- write partials ----
    const size_t SBH = (size_t)B_ * H_ * NSEQ;
    if (lg == 0) {
        mpart[(size_t)sp * SBH + bh * NSEQ + qrow] = cmax;
        lpart[(size_t)sp * SBH + bh * NSEQ + qrow] = csum;
    }
    #pragma unroll
    for (int dt = 0; dt < 4; ++dt)
        #pragma unroll
        for (int r = 0; r < 4; ++r)
            Opart[((size_t)sp * SBH + bh * NSEQ + qt*64 + wv*16 + lg*4 + r) * DKV + dt*16 + li]
                = f2bf(oacc[dt][r]);
}

// ---------------- split combine: merge 16 partials, normalize ----------------
__global__ __launch_bounds__(256, 1) void attn_combine(
    const short* __restrict__ Opart, const float* __restrict__ mpart,
    const float* __restrict__ lpart, short* __restrict__ Ob)
{
    const size_t SBH = (size_t)B_ * H_ * NSEQ;
    const int R = blockIdx.x * 4 + (threadIdx.x >> 6);
    const int d = threadIdx.x & 63;
    const int bh = R >> 10, n = R & (NSEQ - 1);
    const int b = bh >> 4, h = bh & (H_ - 1);

    float ms[NSPLIT], ls[NSPLIT], ov[NSPLIT];
    #pragma unroll
    for (int s = 0; s < NSPLIT; ++s) {
        ms[s] = mpart[(size_t)s * SBH + R];
        ls[s] = lpart[(size_t)s * SBH + R];
        ov[s] = bf2f(Opart[((size_t)s * SBH + R) * DKV + d]);
    }
    float mstar = -1e30f;
    #pragma unroll
    for (int s = 0; s < NSPLIT; ++s) mstar = fmaxf(mstar, ms[s]);
    float lstar = 0.f, acc = 0.f;
    #pragma unroll
    for (int s = 0; s < NSPLIT; ++s) {
        float w = __expf(ms[s] - mstar);
        lstar += w * ls[s];
        acc   += w * ov[s];
    }
    Ob[((size_t)b * NSEQ + n) * DM + h * DKV + d] = f2bf(acc / lstar);
}

// ---------------- residual + LayerNorm ----------------
__global__ __launch_bounds__(256) void ln_kernel(
    const float* __restrict__ Y, const float* __restrict__ gamma,
    const float* __restrict__ beta, float* __restrict__ out)
{
    const int row = blockIdx.x;
    const int t = threadIdx.x;
    const float* y = Y + (size_t)row * DM;
    float4 x = *(const float4*)(y + t*4);
    __shared__ float red[4];
    float s = x.x + x.y + x.z + x.w;
    #pragma unroll
    for (int off = 32; off > 0; off >>= 1) s += __shfl_xor(s, off);
    if ((t & 63) == 0) red[t >> 6] = s;
    __syncthreads();
    float mean = (red[0]+red[1]+red[2]+red[3]) * (1.0f/DM);
    float d0 = x.x-mean, d1 = x.y-mean, d2 = x.z-mean, d3 = x.w-mean;
    float sq = d0*d0 + d1*d1 + d2*d2 + d3*d3;
    __syncthreads();
    #pragma unroll
    for (int off = 32; off > 0; off >>= 1) sq += __shfl_xor(sq, off);
    if ((t & 63) == 0) red[t >> 6] = sq;
    __syncthreads();
    float var = (red[0]+red[1]+red[2]+red[3]) * (1.0f/DM);
    float rstd = rsqrtf(var + LNEPS);
    int c = t * 4;
    float4 g  = *(const float4*)(gamma + c);
    float4 bb = *(const float4*)(beta + c);
    float4 o;
    o.x = d0*rstd*g.x + bb.x;
    o.y = d1*rstd*g.y + bb.y;
    o.z = d2*rstd*g.z + bb.z;
    o.w = d3*rstd*g.w + bb.w;
    *(float4*)(out + (size_t)row*DM + c) = o;
}

extern "C" void kernel_launch(void* const* d_in, const int* in_sizes, int n_in,
                              void* d_out, int out_size, void* d_ws, size_t ws_size,
                              hipStream_t stream)
{
    const float* queries = (const float*)d_in[0];
    const float* keys    = (const float*)d_in[1];
    const float* values  = (const float*)d_in[2];
    const void*  mask    = d_in[3];
    const float* wgt     = (const float*)d_in[4];
    const float* Wq = (const float*)d_in[5];  const float* bq = (const float*)d_in[6];
    const float* Wk = (const float*)d_in[7];  const float* bk = (const float*)d_in[8];
    const float* Wv = (const float*)d_in[9];  const float* bv = (const float*)d_in[10];
    const float* Wo = (const float*)d_in[11]; const float* bo = (const float*)d_in[12];
    const float* gamma = (const float*)d_in[13]; const float* beta = (const float*)d_in[14];
    float* out = (float*)d_out;

    const size_t SZ  = (size_t)B_ * NSEQ * DM;     // 2M elements
    const size_t WSZ = (size_t)DM * DM;            // 1M elements
    const size_t SBH = (size_t)B_ * H_ * NSEQ;     // 32K rows

    char* ws = (char*)d_ws;
    int*   flag = (int*)ws;
    short* Wtq = (short*)(ws + 256);               // Wtq|Wtk|Wtv contiguous = Wcat
    short* Wtk = Wtq + WSZ;
    short* Wtv = Wtk + WSZ;
    short* Wto = Wtv + WSZ;
    short* Qh  = Wto + WSZ;
    short* Kh  = Qh + SZ;
    short* Vth = Kh + SZ;
    short* Opart = Vth + SZ;                       // 16 x 4 MB bf16
    float* mpart = (float*)(Opart + (size_t)NSPLIT * SBH * DKV);
    float* lpart = mpart + NSPLIT * SBH;
    short* Ob  = (short*)(lpart + NSPLIT * SBH);
    float* Yb  = (float*)Opart;                    // alias: Opart dead after combine

    detect_mask<<<1, 1, 0, stream>>>((const unsigned*)mask, flag);
    castT4_bf16<<<dim3(32, 32, 4), 256, 0, stream>>>(Wq, Wk, Wv, Wo, Wtq, Wtk, Wtv, Wto);

    gemm_qkv<<<dim3(48, 32), 256, 0, stream>>>(queries, keys, values, Wtq,
                                               bq, bk, bv, Qh, Kh, Vth);

    attn_one<<<dim3(16 * NSPLIT, H_, B_), 256, 0, stream>>>(
        Qh, Kh, Vth, mask, wgt, flag, Opart, mpart, lpart);
    attn_combine<<<dim3((int)(SBH / 4)), 256, 0, stream>>>(Opart, mpart, lpart, Ob);

    gemm_out<<<dim3(16, 32), 256, 0, stream>>>(Ob, Wto, bo, queries, Yb);
    ln_kernel<<<dim3(B_*NSEQ), 256, 0, stream>>>(Yb, gamma, beta, out);
}